// Round 1
// baseline (163.052 us; speedup 1.0000x reference)
//
#include <hip/hip_runtime.h>
#include <math.h>

#define L_SEQ 2048
#define DMODEL 1024
#define HEADS 16
#define HD 64
#define BATCH 2
#define MROWS (BATCH*L_SEQ)   // 4096
#define KDIM 1024
#define VSTRIDE 2136          // v^T row stride (shorts): 64 front pad + 2048 + 24 tail

typedef short bfrag8 __attribute__((ext_vector_type(8)));   // 8 bf16 = 4 VGPRs
typedef float f32x4f __attribute__((ext_vector_type(4)));

__device__ __forceinline__ unsigned short f2bf(float f) {
    unsigned u = __float_as_uint(f);
    unsigned r = u + 0x7FFFu + ((u >> 16) & 1u);   // RNE
    return (unsigned short)(r >> 16);
}
__device__ __forceinline__ float bf2f(unsigned short h) {
    return __uint_as_float(((unsigned)h) << 16);
}

// ---------------- fp32 -> bf16 convert (x + 4 weights) + zero kmean_acc ------
__global__ __launch_bounds__(256) void convert_bf16(
    const float* __restrict__ x, const float* __restrict__ wq,
    const float* __restrict__ wk, const float* __restrict__ wv,
    const float* __restrict__ wo,
    unsigned short* __restrict__ xb, unsigned short* __restrict__ qwb,
    unsigned short* __restrict__ kwb, unsigned short* __restrict__ vwb,
    unsigned short* __restrict__ owb, float* __restrict__ kmean_acc)
{
    const int bid = blockIdx.x;
    if (bid == 8192) {
        float4 z = make_float4(0.f, 0.f, 0.f, 0.f);
        *(float4*)&kmean_acc[threadIdx.x * 8]     = z;
        *(float4*)&kmean_acc[threadIdx.x * 8 + 4] = z;
        return;
    }
    const float* src; unsigned short* dst; size_t base;
    if (bid < 4096) { src = x; dst = xb; base = (size_t)bid * 1024; }
    else {
        const int r = bid - 4096; const int w = r >> 10; const int off = r & 1023;
        src = (w==0) ? wq : (w==1) ? wk : (w==2) ? wv : wo;
        dst = (w==0) ? qwb : (w==1) ? kwb : (w==2) ? vwb : owb;
        base = (size_t)off * 1024;
    }
    const size_t idx = base + (size_t)threadIdx.x * 4;
    float4 v = *(const float4*)&src[idx];
    ushort4 o;
    o.x = f2bf(v.x); o.y = f2bf(v.y); o.z = f2bf(v.z); o.w = f2bf(v.w);
    *(ushort4*)&dst[idx] = o;
}

// ---------------- 8-phase 256x256 MFMA QKV GEMM (T2+T3+T4+T5) ---------------
// BM=BN=256, BK=64, 8 waves (2M x 4N), 512 threads, 128 KiB LDS.
// LDS = 2 dbuf x 2 half-tiles(128x64) per operand, XOR-swizzled: LDS[row][cg]
// holds global k-group (cg ^ (row&7)) -> conflict-free ds_read_b128 (verified
// 0 conflicts on the previous 2-phase kernel with the same scheme).
// Per K-tile: 4 phases computing block C-quadrants Q00,Q01,Q11,Q10 (A-half and
// BOTH B-half frags held in regs => each LDS half-tile read in exactly 1 phase),
// staging stream A1(t+1) | A0,B0,B1(t+2) at P1..P4. Counted vmcnt(6) ONCE per
// K-tile (phase 4) retires exactly tile t+1's 4 half-tiles; 3 stay in flight.
// Never vmcnt(0) in steady state (T4). setprio(1) around MFMA clusters (T5).
#define GBK 64
#define NT16 (KDIM/64)   // 16 K-tiles

__device__ __forceinline__ void stage_half(short* lds, int buf, int h,
    const unsigned short* __restrict__ src, int rowbase, int ktile,
    int srw, int sgc, int wb)
{
    // 128x64 half-tile: 512 threads x 2 issues x 16B. LDS dest is wave-uniform
    // base + lane*16 (HW rule); rows r and r+64 share (row&7) so one sgc works.
    const unsigned short* s0 =
        src + (size_t)(rowbase + h*128 + srw) * KDIM + ktile*64 + sgc;
    __builtin_amdgcn_global_load_lds(
        (const __attribute__((address_space(1))) void*)s0,
        (__attribute__((address_space(3))) void*)&lds[buf*16384 + h*8192 + wb],
        16, 0, 0);
    __builtin_amdgcn_global_load_lds(
        (const __attribute__((address_space(1))) void*)(s0 + (size_t)64*KDIM),
        (__attribute__((address_space(3))) void*)&lds[buf*16384 + h*8192 + 4096 + wb],
        16, 0, 0);
}

__device__ __forceinline__ void read_a(const short* As, int base, int row0,
                                       int lm, int quad, bfrag8 (&afh)[4][2])
{
#pragma unroll
    for (int mt = 0; mt < 4; ++mt) {
        const int ar = row0 + mt*16 + lm;
        const int arb = base + ar*64;
        afh[mt][0] = *(const bfrag8*)&As[arb + ((quad ^ (ar & 7)) << 3)];
        afh[mt][1] = *(const bfrag8*)&As[arb + (((4 + quad) ^ (ar & 7)) << 3)];
    }
}

__device__ __forceinline__ void read_b(const short* Bs, int base, int row0,
                                       int lm, int quad, bfrag8 (&bf)[2][2])
{
#pragma unroll
    for (int nt = 0; nt < 2; ++nt) {
        const int br = row0 + nt*16 + lm;
        const int brb = base + br*64;
        bf[nt][0] = *(const bfrag8*)&Bs[brb + ((quad ^ (br & 7)) << 3)];
        bf[nt][1] = *(const bfrag8*)&Bs[brb + (((4 + quad) ^ (br & 7)) << 3)];
    }
}

__device__ __forceinline__ void mfma16(const bfrag8 (&afh)[4][2],
                                       const bfrag8 (&bf)[2][2],
                                       f32x4f (&acc)[8][4], int mh, int nh)
{
    __builtin_amdgcn_s_setprio(1);
#pragma unroll
    for (int mt = 0; mt < 4; ++mt)
#pragma unroll
        for (int nt = 0; nt < 2; ++nt) {
            f32x4f a = acc[mh*4 + mt][nh*2 + nt];
            a = __builtin_amdgcn_mfma_f32_16x16x32_bf16(afh[mt][0], bf[nt][0], a, 0, 0, 0);
            a = __builtin_amdgcn_mfma_f32_16x16x32_bf16(afh[mt][1], bf[nt][1], a, 0, 0, 0);
            acc[mh*4 + mt][nh*2 + nt] = a;
        }
    __builtin_amdgcn_s_setprio(0);
}

__global__ __launch_bounds__(512, 2) void mfma_gemm_qkv(
    const unsigned short* __restrict__ A,
    const unsigned short* __restrict__ W0, const unsigned short* __restrict__ W1,
    const unsigned short* __restrict__ W2,
    unsigned short* __restrict__ qo, unsigned short* __restrict__ ko,
    unsigned short* __restrict__ vo, float* __restrict__ kmean_acc)
{
    __shared__ short As[2*256*GBK];   // 64 KB: [buf][half(128 rows)][row][64k swz]
    __shared__ short Bs[2*256*GBK];   // 64 KB

    const int tid  = threadIdx.x;
    const int wave = tid >> 6, lane = tid & 63;
    const int quad = lane >> 4, lm = lane & 15;
    const int wm = wave >> 2, wn = wave & 3;        // 2M x 4N wave grid

    const int m0  = blockIdx.x * 256;
    const int n0g = blockIdx.y * 256;
    const int which = n0g >> 10;                    // uniform: 256 | 1024
    const int n0 = n0g & 1023;
    const unsigned short* Wp = (which==0) ? W0 : (which==1) ? W1 : W2;

    // staging geometry
    const int srw = tid >> 3;                       // 0..63
    const int sgc = (((tid & 7) ^ (srw & 7)) << 3); // pre-swizzled global col
    const int wb  = wave << 9;                      // wave-uniform LDS base

    // -------- prologue: stream order A0,B0,B1,A1(t0) | A0,B0,B1(t1) --------
    stage_half(As, 0, 0, A,  m0, 0, srw, sgc, wb);
    stage_half(Bs, 0, 0, Wp, n0, 0, srw, sgc, wb);
    stage_half(Bs, 0, 1, Wp, n0, 0, srw, sgc, wb);
    stage_half(As, 0, 1, A,  m0, 0, srw, sgc, wb);
    asm volatile("s_waitcnt vmcnt(4)" ::: "memory");
    stage_half(As, 1, 0, A,  m0, 1, srw, sgc, wb);
    stage_half(Bs, 1, 0, Wp, n0, 1, srw, sgc, wb);
    stage_half(Bs, 1, 1, Wp, n0, 1, srw, sgc, wb);
    asm volatile("s_waitcnt vmcnt(6)" ::: "memory"); // tile0 fully landed
    __builtin_amdgcn_s_barrier();

    bfrag8 afh[4][2], bf0[2][2], bf1[2][2];
    f32x4f acc[8][4] = {};

    for (int t = 0; t < NT16; ++t) {
        const int cur = t & 1, nxt = cur ^ 1;
        const int cb = cur * 16384;

        // P1 (Q00): A-half0 + B-half0; stage A1(t+1) -> nxt
        read_a(As, cb, wm*64, lm, quad, afh);
        read_b(Bs, cb, wn*32, lm, quad, bf0);
        if (t + 1 < NT16) stage_half(As, nxt, 1, A, m0, t+1, srw, sgc, wb);
        asm volatile("s_waitcnt lgkmcnt(8)" ::: "memory");
        __builtin_amdgcn_s_barrier();
        asm volatile("s_waitcnt lgkmcnt(0)" ::: "memory");
        mfma16(afh, bf0, acc, 0, 0);
        __builtin_amdgcn_s_barrier();

        // P2 (Q01): B-half1; stage A0(t+2) -> cur (A-half0 last read at P1)
        read_b(Bs, cb, 128 + wn*32, lm, quad, bf1);
        if (t + 2 < NT16) stage_half(As, cur, 0, A, m0, t+2, srw, sgc, wb);
        __builtin_amdgcn_s_barrier();
        asm volatile("s_waitcnt lgkmcnt(0)" ::: "memory");
        mfma16(afh, bf1, acc, 0, 1);
        __builtin_amdgcn_s_barrier();

        // P3 (Q11): A-half1; stage B0(t+2) -> cur (B-half0 last read at P1)
        read_a(As, cb, 128 + wm*64, lm, quad, afh);
        if (t + 2 < NT16) stage_half(Bs, cur, 0, Wp, n0, t+2, srw, sgc, wb);
        __builtin_amdgcn_s_barrier();
        asm volatile("s_waitcnt lgkmcnt(0)" ::: "memory");
        mfma16(afh, bf1, acc, 1, 1);
        __builtin_amdgcn_s_barrier();

        // P4 (Q10): regs only; stage B1(t+2) -> cur (B-half1 last read at P2)
        if (t + 2 < NT16) stage_half(Bs, cur, 1, Wp, n0, t+2, srw, sgc, wb);
        __builtin_amdgcn_s_barrier();
        mfma16(afh, bf0, acc, 1, 0);
        // once-per-K-tile counted wait: retires exactly tile t+1's 4 halves,
        // leaves 3 half-tiles (tile t+2) in flight. Tail: drain at NT-2.
        if (t < NT16 - 2)       { asm volatile("s_waitcnt vmcnt(6)" ::: "memory"); }
        else if (t == NT16 - 2) { asm volatile("s_waitcnt vmcnt(0)" ::: "memory"); }
        __builtin_amdgcn_s_barrier();
    }

    // -------- epilogue: C/D layout col=lane&15, row=quad*4+reg --------
    if (which == 2) {
        // v: transposed padded layout, coalesced ushort4 (4 consecutive l)
#pragma unroll
        for (int mh = 0; mh < 2; ++mh)
#pragma unroll
        for (int mt = 0; mt < 4; ++mt)
#pragma unroll
        for (int nh = 0; nh < 2; ++nh)
#pragma unroll
        for (int nt = 0; nt < 2; ++nt) {
            const int gn = n0 + nh*128 + wn*32 + nt*16 + lm;
            const int h = gn >> 6, d = gn & 63;
            const int gm0 = m0 + mh*128 + wm*64 + mt*16 + quad*4;
            const int b = gm0 >> 11, l0 = gm0 & (L_SEQ-1);
            const f32x4f a = acc[mh*4+mt][nh*2+nt];
            ushort4 o;
            o.x = f2bf(a[0]); o.y = f2bf(a[1]);
            o.z = f2bf(a[2]); o.w = f2bf(a[3]);
            *(ushort4*)&vo[((size_t)((b*HEADS + h)*HD + d))*VSTRIDE + 64 + l0] = o;
        }
    } else {
        unsigned short* Cp = (which==0) ? qo : ko;
#pragma unroll
        for (int mh = 0; mh < 2; ++mh)
#pragma unroll
        for (int mt = 0; mt < 4; ++mt)
#pragma unroll
        for (int nh = 0; nh < 2; ++nh)
#pragma unroll
        for (int nt = 0; nt < 2; ++nt) {
            const int gn = n0 + nh*128 + wn*32 + nt*16 + lm;
            const int h = gn >> 6, d = gn & 63;
            const f32x4f a = acc[mh*4+mt][nh*2+nt];
#pragma unroll
            for (int r = 0; r < 4; ++r) {
                const int gm = m0 + mh*128 + wm*64 + mt*16 + quad*4 + r;
                const int b = gm >> 11, l = gm & (L_SEQ-1);
                Cp[(((size_t)(b*HEADS + h) * L_SEQ) + l) * HD + d] = f2bf(a[r]);
            }
        }
        if (which == 1) {
            const int b = m0 >> 11;     // 256 | 2048 -> uniform per block
#pragma unroll
            for (int nh = 0; nh < 2; ++nh)
#pragma unroll
            for (int nt = 0; nt < 2; ++nt) {
                const int gn = n0 + nh*128 + wn*32 + nt*16 + lm;
                const int h = gn >> 6, d = gn & 63;
                float s = 0.f;
#pragma unroll
                for (int mh = 0; mh < 2; ++mh)
#pragma unroll
                for (int mt = 0; mt < 4; ++mt)
#pragma unroll
                for (int r = 0; r < 4; ++r) s += acc[mh*4+mt][nh*2+nt][r];
                atomicAdd(&kmean_acc[(size_t)(b*HEADS + h)*HD + d], s);
            }
        }
    }
}

// ---------------- out-projection GEMM: 64x128 tiles (M-split for occupancy) --
__global__ void out_proj_gemm(
    const unsigned short* __restrict__ A, const unsigned short* __restrict__ W,
    float* __restrict__ C)
{
    __shared__ short As[64*GBK];    // 8 KB
    __shared__ short Bs[128*GBK];   // 16 KB

    const int tid  = threadIdx.x;
    const int wave = tid >> 6, lane = tid & 63;
    const int m0   = blockIdx.x * 64;
    const int n0   = blockIdx.y * 128;

    const int quad = lane >> 4, lm = lane & 15;
    const int wm = wave >> 1, wn = wave & 1;   // wave tile: 32 rows x 64 cols

    f32x4f acc[2][4] = {};

    const int sea   = wave * 1024 + lane * 8;
    const int srowa = sea >> 6;
    const int sga   = ((((sea & 63) >> 3) ^ (srowa & 7)) << 3);
    const int seb   = wave * 2048 + lane * 8;
    const int srowb = seb >> 6;
    const int sgb   = ((((seb & 63) >> 3) ^ (srowb & 7)) << 3);

    for (int k0 = 0; k0 < KDIM; k0 += GBK) {
        __syncthreads();
        #pragma unroll
        for (int i = 0; i < 2; ++i) {
            const int ebase = wave * 1024 + i * 512;
            const int row = srowa + i * 8;
            __builtin_amdgcn_global_load_lds(
                (const __attribute__((address_space(1))) void*)(A + (size_t)(m0 + row) * KDIM + k0 + sga),
                (__attribute__((address_space(3))) void*)(&As[ebase]), 16, 0, 0);
        }
        #pragma unroll
        for (int i = 0; i < 4; ++i) {
            const int ebase = wave * 2048 + i * 512;
            const int row = srowb + i * 8;
            __builtin_amdgcn_global_load_lds(
                (const __attribute__((address_space(1))) void*)(W + (size_t)(n0 + row) * KDIM + k0 + sgb),
                (__attribute__((address_space(3))) void*)(&Bs[ebase]), 16, 0, 0);
        }
        __syncthreads();

        #pragma unroll
        for (int kk = 0; kk < 2; ++kk) {
            bfrag8 af[2], bf[4];
            #pragma unroll
            for (int t = 0; t < 2; ++t) {
                const int ar = wm*32 + t*16 + lm;
                af[t] = *(const bfrag8*)&As[ar*GBK + (((kk*4 + quad) ^ (ar & 7)) << 3)];
            }
            #pragma unroll
            for (int t = 0; t < 4; ++t) {
                const int br = wn*64 + t*16 + lm;
                bf[t] = *(const bfrag8*)&Bs[br*GBK + (((kk*4 + quad) ^ (br & 7)) << 3)];
            }
            #pragma unroll
            for (int mt = 0; mt < 2; ++mt)
                #pragma unroll
                for (int nt = 0; nt < 4; ++nt)
                    acc[mt][nt] = __builtin_amdgcn_mfma_f32_16x16x32_bf16(
                        af[mt], bf[nt], acc[mt][nt], 0, 0, 0);
        }
    }

    #pragma unroll
    for (int mt = 0; mt < 2; ++mt)
        #pragma unroll
        for (int nt = 0; nt < 4; ++nt) {
            const int gn = n0 + wn*64 + nt*16 + lm;
            #pragma unroll
            for (int r = 0; r < 4; ++r) {
                const int gm = m0 + wm*32 + mt*16 + quad*4 + r;
                C[(size_t)gm * DMODEL + gn] = acc[mt][nt][r];
            }
        }
}

// ---------------- MFMA windowed attention, zero-staging ----------------
#define P_STRIDE 104    // shorts

__global__ __launch_bounds__(256) void attn_kernel(
    const unsigned short* __restrict__ qb, const unsigned short* __restrict__ kb,
    const unsigned short* __restrict__ vt, const float* __restrict__ kmean_acc,
    const float* __restrict__ g_sep, const float* __restrict__ g_align,
    const float* __restrict__ g_coh, unsigned short* __restrict__ out)
{
    __shared__ unsigned short pl[64 * P_STRIDE];

    const int tid = threadIdx.x;
    const int bh = blockIdx.x >> 5;        // 32 q-tiles per (b,h)
    const int qt = blockIdx.x & 31;
    const int q0 = qt * 64;
    const int j0 = q0 - 64;

    const int w = tid >> 6, lane = tid & 63;
    const int quad = lane >> 4, lm = lane & 15;
    const float sep = g_sep[0], align = g_align[0], coh = g_coh[0];

    const unsigned short* kbh = kb + (size_t)bh * L_SEQ * HD;
    const unsigned short* vbh = vt + (size_t)bh * HD * VSTRIDE;

    const unsigned short* qrow =
        qb + ((size_t)bh * L_SEQ + q0 + w*16 + lm) * HD + quad * 8;
    bfrag8 qa0 = *(const bfrag8*)qrow;
    bfrag8 qa1 = *(const bfrag8*)(qrow + 32);

    const float* kmp = kmean_acc + bh * HD + quad * 8;
    float4 km0 = *(const float4*)(kmp);
    float4 km1 = *(const float4*)(kmp + 4);
    float4 km2 = *(const float4*)(kmp + 32);
    float4 km3 = *(const float4*)(kmp + 36);
    float part =
        bf2f((unsigned short)qa0[0])*km0.x + bf2f((unsigned short)qa0[1])*km0.y +
        bf2f((unsigned short)qa0[2])*km0.z + bf2f((unsigned short)qa0[3])*km0.w +
        bf2f((unsigned short)qa0[4])*km1.x + bf2f((unsigned short)qa0[5])*km1.y +
        bf2f((unsigned short)qa0[6])*km1.z + bf2f((unsigned short)qa0[7])*km1.w +
        bf2f((unsigned short)qa1[0])*km2.x + bf2f((unsigned short)qa1[1])*km2.y +
        bf2f((unsigned short)qa1[2])*km2.z + bf2f((unsigned short)qa1[3])*km2.w +
        bf2f((unsigned short)qa1[4])*km3.x + bf2f((unsigned short)qa1[5])*km3.y +
        bf2f((unsigned short)qa1[6])*km3.z + bf2f((unsigned short)qa1[7])*km3.w;
    part *= (1.f / (float)L_SEQ);
    part += __shfl_xor(part, 16, 64);
    part += __shfl_xor(part, 32, 64);

    f32x4f sacc[6];
    #pragma unroll
    for (int t = 0; t < 6; ++t) {
        int kr = j0 + w*16 + t*16 + lm;
        kr = kr < 0 ? 0 : (kr >= L_SEQ ? L_SEQ - 1 : kr);
        const unsigned short* kp = kbh + (size_t)kr * HD + quad * 8;
        bfrag8 b0 = *(const bfrag8*)kp;
        bfrag8 b1 = *(const bfrag8*)(kp + 32);
        f32x4f z = {0.f, 0.f, 0.f, 0.f};
        z = __builtin_amdgcn_mfma_f32_16x16x32_bf16(qa0, b0, z, 0, 0, 0);
        sacc[t] = __builtin_amdgcn_mfma_f32_16x16x32_bf16(qa1, b1, z, 0, 0, 0);
    }

    float rinv[4];
    #pragma unroll
    for (int r = 0; r < 4; ++r) {
        const int row = quad*4 + r;
        const int i   = q0 + w*16 + row;
        const float mean_i = __shfl(part, row, 64) * 0.125f;
        float sc[6]; float mx = -3.0e38f;
        #pragma unroll
        for (int t = 0; t < 6; ++t) {
            const int jabs = j0 + w*16 + t*16 + lm;
            const int dist = i - jabs;
            float s = sacc[t][r] * 0.125f;
            const float sig = 1.f / (1.f + __expf(-s));
            float adj = s * (1.f + align) - sep * sig * sig - coh * fabsf(s - mean_i);
            const bool ok = (dist >= 0) && (dist < 64) && (jabs >= 0);
            sc[t] = ok ? adj : -3.0e38f;
            mx = fmaxf(mx, sc[t]);
        }
        mx = fmaxf(mx, __shfl_xor(mx, 1, 64));
        mx = fmaxf(mx, __shfl_xor(mx, 2, 64));
        mx = fmaxf(mx, __shfl_xor(mx, 4, 64));
        mx = fmaxf(mx, __shfl_xor(mx, 8, 64));
        float ls = 0.f;
        #pragma unroll
        for (int t = 0; t < 6; ++t) {
            const float p = __expf(sc[t] - mx);   // masked -> 0
            ls += p;
            pl[(w*16 + row) * P_STRIDE + t*16 + lm] = f2bf(p);
        }
        ls += __shfl_xor(ls, 1, 64);
        ls += __shfl_xor(ls, 2, 64);
        ls += __shfl_xor(ls, 4, 64);
        ls += __shfl_xor(ls, 8, 64);
        rinv[r] = 1.f / ls;
    }

    f32x4f oacc[4] = {};
    #pragma unroll
    for (int kk = 0; kk < 3; ++kk) {
        bfrag8 pa = *(const bfrag8*)&pl[(w*16 + lm) * P_STRIDE + kk*32 + quad*8];
        const int loff = 64 + j0 + w*16 + kk*32 + quad*8;
        #pragma unroll
        for (int nt = 0; nt < 4; ++nt) {
            bfrag8 bv = *(const bfrag8*)&vbh[(size_t)(nt*16 + lm) * VSTRIDE + loff];
            oacc[nt] = __builtin_amdgcn_mfma_f32_16x16x32_bf16(pa, bv, oacc[nt], 0, 0, 0);
        }
    }

    const int b = bh >> 4, h = bh & (HEADS - 1);
    #pragma unroll
    for (int nt = 0; nt < 4; ++nt)
        #pragma unroll
        for (int r = 0; r < 4; ++r) {
            const int i = q0 + w*16 + quad*4 + r;
            const int d = nt*16 + lm;
            out[((size_t)(b * L_SEQ + i)) * DMODEL + h * HD + d] =
                f2bf(oacc[nt][r] * rinv[r]);
        }
}

extern "C" void kernel_launch(void* const* d_in, const int* in_sizes, int n_in,
                              void* d_out, int out_size, void* d_ws, size_t ws_size,
                              hipStream_t stream)
{
    (void)in_sizes; (void)n_in; (void)out_size; (void)ws_size;
    const float* x     = (const float*)d_in[0];
    const float* Wq    = (const float*)d_in[1];
    const float* Wk    = (const float*)d_in[2];
    const float* Wv    = (const float*)d_in[3];
    const float* Wo    = (const float*)d_in[4];
    const float* g_sep   = (const float*)d_in[5];
    const float* g_align = (const float*)d_in[6];
    const float* g_coh   = (const float*)d_in[7];
    float* out = (float*)d_out;

    // workspace layout (~49 MB)
    float* kmean_ws = (float*)d_ws;                   // 2048 floats (sum, not mean)
    unsigned short* xb  = (unsigned short*)(kmean_ws + 2048);
    const size_t per = (size_t)MROWS * DMODEL;        // 4 Mi
    unsigned short* wqb = xb  + per;
    unsigned short* wkb = wqb + (size_t)DMODEL*KDIM;
    unsigned short* wvb = wkb + (size_t)DMODEL*KDIM;
    unsigned short* wob = wvb + (size_t)DMODEL*KDIM;
    unsigned short* qb  = wob + (size_t)DMODEL*KDIM;
    unsigned short* kb  = qb  + per;
    unsigned short* vtb = kb  + per;                  // [b,h,d,*] padded: 2048*VSTRIDE
    unsigned short* attb = vtb + (size_t)BATCH*HEADS*HD*VSTRIDE;

    convert_bf16<<<dim3(8193), dim3(256), 0, stream>>>(
        x, Wq, Wk, Wv, Wo, xb, wqb, wkb, wvb, wob, kmean_ws);
    mfma_gemm_qkv<<<dim3(MROWS/256, 3*DMODEL/256), dim3(512), 0, stream>>>(
        xb, wqb, wkb, wvb, qb, kb, vtb, kmean_ws);
    attn_kernel<<<dim3(BATCH*HEADS*(L_SEQ/64)), dim3(256), 0, stream>>>(
        qb, kb, vtb, kmean_ws, g_sep, g_align, g_coh, attb);
    out_proj_gemm<<<dim3(MROWS/64, DMODEL/128), dim3(256), 0, stream>>>(
        attb, wob, out);
}